// Round 5
// baseline (96.461 us; speedup 1.0000x reference)
//
#include <hip/hip_runtime.h>
#include <math.h>

typedef _Float16 h16;
typedef _Float16 h8 __attribute__((ext_vector_type(8)));
typedef float f32x4 __attribute__((ext_vector_type(4)));

__device__ inline void gl2lds16(const void* g, void* l) {
  __builtin_amdgcn_global_load_lds(
      (const __attribute__((address_space(1))) void*)g,
      (__attribute__((address_space(3))) void*)l, 16, 0, 0);
}

__device__ inline void barrier_raw() {
  asm volatile("" ::: "memory");
  __builtin_amdgcn_s_barrier();
  asm volatile("" ::: "memory");
}

#define VMCNT(N) asm volatile("s_waitcnt vmcnt(" #N ")" ::: "memory")

// ---------------- fused fp32 -> fp16 conversion (hs + 4 weights) ----------------
__global__ __launch_bounds__(256) void f2h_all(
    const float* __restrict__ hs, const float* __restrict__ w0,
    const float* __restrict__ w1, const float* __restrict__ w2,
    const float* __restrict__ w3, h16* __restrict__ dst, int hsN) {
  int i = (blockIdx.x * 256 + threadIdx.x) * 8;
  const int tot = hsN + 4 * 1048576;
  if (i >= tot) return;
  const float* src;
  int off;
  if (i < hsN) {
    src = hs; off = i;
  } else {
    int k = i - hsN;
    int seg = k >> 20;
    off = k & 1048575;
    src = seg == 0 ? w0 : seg == 1 ? w1 : seg == 2 ? w2 : w3;
  }
  float4 a = *(const float4*)(src + off);
  float4 b = *(const float4*)(src + off + 4);
  h8 o;
  o[0] = (h16)a.x; o[1] = (h16)a.y; o[2] = (h16)a.z; o[3] = (h16)a.w;
  o[4] = (h16)b.x; o[5] = (h16)b.y; o[6] = (h16)b.z; o[7] = (h16)b.w;
  *(h8*)(dst + i) = o;
}

// ---------------- GEMM template: BK=32, LDS triple-buffer, 2-tile prefetch ----
// Per tile t: stage(t+2) -> VMCNT(8) -> barrier -> ds_read frags -> MFMA -> barrier.
// FIFO ledger: after stage issue, outstanding (per wave) <= {t+1,t+2} = 8 newest,
// so vmcnt(8) guarantees tile t's 4 calls landed; barrier publishes across waves.
// WAR: stage(t+2) writes buf (t+2)%3 == (t-1)%3 whose reads completed before
// tile t-1's closing barrier. Swizzle: LDS[row][s] holds global slot
// s ^ ((row>>1)&3) (16B slots); inverse-swizzled global source, swizzled read.
// MODE 0: QKV fused (bias q/k/v, scatter [B,H,S,D] fp16).
// MODE 1: final projection (fp32 out + bias).
template <int BM, int BN, int TH, int WN, int MODE>
__global__ __launch_bounds__(TH) void gemm3(
    const h16* __restrict__ A, const h16* __restrict__ Bw,
    const float* __restrict__ b0, const float* __restrict__ b1,
    const float* __restrict__ b2, h16* __restrict__ qo, h16* __restrict__ ko,
    h16* __restrict__ vo, float* __restrict__ Cf, int nbm, int cpx) {
  constexpr int WAVES = TH / 64;
  constexpr int WM = WAVES / WN;
  constexpr int MR = BM / WM / 16;
  constexpr int NR = BN / WN / 16;
  constexpr int NK = 32;        // K = 1024 = 32 tiles of 32
  constexpr int RPC = TH / 4;   // rows staged per gl_lds call

  __shared__ __align__(16) h16 Ash[3][BM][32];
  __shared__ __align__(16) h16 Bsh[3][BN][32];

  const int tid = threadIdx.x;
  const int wid = tid >> 6, lane = tid & 63;
  const int lr = lane & 15, lg = lane >> 4;
  const int wr = wid / WN, wc = wid % WN;
  const int srw = tid >> 2;  // staging row within a call (row%RPC)
  const int ssl = tid & 3;   // staging 16B slot
  const int csw = (ssl ^ ((srw >> 1) & 3)) * 8;  // inverse-swizzled col (h16)

  const int wg = (blockIdx.x % 8) * cpx + blockIdx.x / 8;
  const int bm = wg % nbm, bn = wg / nbm;
  const int row0 = bm * BM, col0 = bn * BN;

  const h16* Ag = A + (size_t)row0 * 1024;
  const h16* Bg = Bw + (size_t)col0 * 1024;

  auto stage = [&](int t, int bi) {
    const int kof = t * 32 + csw;
#pragma unroll
    for (int rs = 0; rs < BM; rs += RPC)
      gl2lds16(Ag + (size_t)(rs + srw) * 1024 + kof, &Ash[bi][rs + wid * 16][0]);
#pragma unroll
    for (int rs = 0; rs < BN; rs += RPC)
      gl2lds16(Bg + (size_t)(rs + srw) * 1024 + kof, &Bsh[bi][rs + wid * 16][0]);
  };

  auto ldf = [&](const h16* base, int row) -> h8 {
    return *(const h8*)(base + row * 32 + (lg ^ ((row >> 1) & 3)) * 8);
  };

  f32x4 acc[MR][NR] = {};

  // prologue: stage tiles 0,1 ; wait tile 0 (4 newest = tile 1 still in flight)
  stage(0, 0);
  stage(1, 1);
  VMCNT(4);
  barrier_raw();

  for (int t = 0; t < NK; ++t) {
    const int rb = t % 3;
    if (t + 2 < NK) stage(t + 2, (t + 2) % 3);
    VMCNT(8);
    barrier_raw();
    h8 af[MR], bf[NR];
#pragma unroll
    for (int m = 0; m < MR; ++m)
      af[m] = ldf(&Ash[rb][0][0], wr * (BM / WM) + m * 16 + lr);
#pragma unroll
    for (int n = 0; n < NR; ++n)
      bf[n] = ldf(&Bsh[rb][0][0], wc * (BN / WN) + n * 16 + lr);
    __builtin_amdgcn_s_setprio(1);
#pragma unroll
    for (int m = 0; m < MR; ++m)
#pragma unroll
      for (int n = 0; n < NR; ++n)
        acc[m][n] =
            __builtin_amdgcn_mfma_f32_16x16x32_f16(af[m], bf[n], acc[m][n], 0, 0, 0);
    __builtin_amdgcn_s_setprio(0);
    barrier_raw();
  }

  if (MODE == 0) {
    // bias + scatter to [B,H,S,D] fp16
    const int tsel = col0 >> 10;
    const float* bp = tsel == 0 ? b0 : (tsel == 1 ? b1 : b2);
    h16* outp = tsel == 0 ? qo : (tsel == 1 ? ko : vo);
#pragma unroll
    for (int n = 0; n < NR; ++n) {
      const int cidx = col0 + wc * (BN / WN) + n * 16 + lr;
      const int jj = cidx & 1023;
      const float bv = bp[jj];
      const int hh = jj >> 6, dd = jj & 63;
#pragma unroll
      for (int m = 0; m < MR; ++m) {
#pragma unroll
        for (int j = 0; j < 4; ++j) {
          const int r = row0 + wr * (BM / WM) + m * 16 + lg * 4 + j;
          const int bb = r >> 11, ss = r & 2047;
          outp[(((size_t)bb * 16 + hh) * 2048 + ss) * 64 + dd] =
              (h16)(acc[m][n][j] + bv);
        }
      }
    }
  } else {
#pragma unroll
    for (int n = 0; n < NR; ++n) {
      const int cidx = col0 + wc * (BN / WN) + n * 16 + lr;
      const float bv = b0[cidx];
#pragma unroll
      for (int m = 0; m < MR; ++m)
#pragma unroll
        for (int j = 0; j < 4; ++j) {
          const int r = row0 + wr * (BM / WM) + m * 16 + lg * 4 + j;
          Cf[(size_t)r * 1024 + cidx] = acc[m][n][j] + bv;
        }
    }
  }
}

// ---------------- sliding-window attention (unchanged) ----------------
__global__ __launch_bounds__(256) void swattn(const h16* __restrict__ Q,
                                              const h16* __restrict__ K,
                                              const h16* __restrict__ V,
                                              h16* __restrict__ O) {
  __shared__ __align__(16) h16 Ksh[128 * 72];
  __shared__ __align__(16) h16 Vsh[64 * 136];
  __shared__ __align__(16) h16 Psh[4][16 * 136];

  const int qb0 = blockIdx.x * 64;
  const int bh = blockIdx.y;
  const int b = bh >> 4, h = bh & 15;
  const int tid = threadIdx.x;
  const int wave = tid >> 6, lane = tid & 63;
  const int lr = lane & 15, lg = lane >> 4;

  const h16* Qb = Q + (size_t)bh * 2048 * 64;
  const h16* Kb = K + (size_t)bh * 2048 * 64;
  const h16* Vb = V + (size_t)bh * 2048 * 64;

#pragma unroll
  for (int i = 0; i < 4; ++i) {
    const int c = tid * 4 + i;
    const int row = c >> 3, c8 = c & 7;
    const int t = qb0 - 32 + row;
    h8 kv, vv;
    if (t >= 0 && t < 2048) {
      kv = *(const h8*)&Kb[(size_t)t * 64 + c8 * 8];
      vv = *(const h8*)&Vb[(size_t)t * 64 + c8 * 8];
    } else {
#pragma unroll
      for (int j = 0; j < 8; ++j) { kv[j] = (h16)0.f; vv[j] = (h16)0.f; }
    }
    *(h8*)&Ksh[row * 72 + c8 * 8] = kv;
#pragma unroll
    for (int j = 0; j < 8; ++j) Vsh[(c8 * 8 + j) * 136 + row] = vv[j];
  }
  __syncthreads();

  const int qrow = qb0 + wave * 16 + lr;
  h8 qa[2];
#pragma unroll
  for (int kk = 0; kk < 2; ++kk)
    qa[kk] = *(const h8*)&Qb[(size_t)qrow * 64 + kk * 32 + lg * 8];

  f32x4 sacc[8] = {};
#pragma unroll
  for (int n = 0; n < 8; ++n)
#pragma unroll
    for (int kk = 0; kk < 2; ++kk) {
      h8 kb = *(const h8*)&Ksh[(n * 16 + lr) * 72 + kk * 32 + lg * 8];
      sacc[n] = __builtin_amdgcn_mfma_f32_16x16x32_f16(qa[kk], kb, sacc[n], 0, 0, 0);
    }

  float p[8][4];
#pragma unroll
  for (int j = 0; j < 4; ++j) {
    const int wrow = wave * 16 + lg * 4 + j;
    float mx = -1e30f;
#pragma unroll
    for (int n = 0; n < 8; ++n) {
      const int d = n * 16 + lr - wrow;
      float s = (d < 0 || d > 64) ? -1e30f : sacc[n][j] * 0.125f;
      p[n][j] = s;
      mx = fmaxf(mx, s);
    }
#pragma unroll
    for (int off = 1; off < 16; off <<= 1) mx = fmaxf(mx, __shfl_xor(mx, off, 64));
    float sum = 0.f;
#pragma unroll
    for (int n = 0; n < 8; ++n) {
      const float e = __expf(p[n][j] - mx);
      p[n][j] = e;
      sum += e;
    }
#pragma unroll
    for (int off = 1; off < 16; off <<= 1) sum += __shfl_xor(sum, off, 64);
    const float inv = 1.f / sum;
#pragma unroll
    for (int n = 0; n < 8; ++n) p[n][j] *= inv;
  }

#pragma unroll
  for (int n = 0; n < 8; ++n)
#pragma unroll
    for (int j = 0; j < 4; ++j)
      Psh[wave][(lg * 4 + j) * 136 + n * 16 + lr] = (h16)p[n][j];
  __syncthreads();

  f32x4 oacc[4] = {};
#pragma unroll
  for (int kk = 0; kk < 4; ++kk) {
    h8 pa = *(const h8*)&Psh[wave][lr * 136 + kk * 32 + lg * 8];
#pragma unroll
    for (int n = 0; n < 4; ++n) {
      h8 vb = *(const h8*)&Vsh[(n * 16 + lr) * 136 + kk * 32 + lg * 8];
      oacc[n] = __builtin_amdgcn_mfma_f32_16x16x32_f16(pa, vb, oacc[n], 0, 0, 0);
    }
  }

#pragma unroll
  for (int n = 0; n < 4; ++n)
#pragma unroll
    for (int j = 0; j < 4; ++j) {
      const int s = qb0 + wave * 16 + lg * 4 + j;
      const int d = n * 16 + lr;
      O[((size_t)b * 2048 + s) * 1024 + h * 64 + d] = (h16)oacc[n][j];
    }
}

extern "C" void kernel_launch(void* const* d_in, const int* in_sizes, int n_in,
                              void* d_out, int out_size, void* d_ws, size_t ws_size,
                              hipStream_t stream) {
  const float* hs = (const float*)d_in[0];
  const float* qw = (const float*)d_in[1];
  const float* qb = (const float*)d_in[2];
  const float* kw = (const float*)d_in[3];
  const float* kb = (const float*)d_in[4];
  const float* vw = (const float*)d_in[5];
  const float* vb = (const float*)d_in[6];
  const float* ow = (const float*)d_in[7];
  const float* ob = (const float*)d_in[8];

  const int M = in_sizes[0] / 1024;  // B * S = 4096

  h16* hsH = (h16*)d_ws;
  h16* wqkv = hsH + (size_t)M * 1024;           // 3072 x 1024 (q,k,v stacked)
  h16* woH = wqkv + (size_t)3072 * 1024;        // 1024 x 1024
  h16* qH = woH + (size_t)1024 * 1024;          // [B,H,S,D]
  h16* kH = qH + (size_t)M * 1024;
  h16* vH = kH + (size_t)M * 1024;
  h16* attnH = vH + (size_t)M * 1024;           // [B,S,E]

  const int tot = M * 1024 + 4 * 1048576;
  f2h_all<<<(tot / 8 + 255) / 256, 256, 0, stream>>>(hs, qw, kw, vw, ow, hsH,
                                                     M * 1024);

  // QKV: 256x256 tiles, grid 16x12 = 192 (192 % 8 == 0 -> bijective swizzle)
  gemm3<256, 256, 512, 4, 0><<<192, 512, 0, stream>>>(
      hsH, wqkv, qb, kb, vb, qH, kH, vH, nullptr, M / 256, 192 / 8);

  swattn<<<dim3(32, M / 2048 * 16), 256, 0, stream>>>(qH, kH, vH, attnH);

  // O-proj: 128x128 tiles, grid 32x8 = 256
  gemm3<128, 128, 256, 2, 1><<<256, 256, 0, stream>>>(
      attnH, woH, ob, nullptr, nullptr, nullptr, nullptr, nullptr,
      (float*)d_out, M / 128, 256 / 8);
}

// Round 6
// 86.811 us; speedup vs baseline: 1.1112x; 1.1112x over previous
//
#include <hip/hip_runtime.h>
#include <math.h>

typedef _Float16 h16;
typedef _Float16 h8 __attribute__((ext_vector_type(8)));
typedef float f32x4 __attribute__((ext_vector_type(4)));

__device__ inline void gl2lds16(const void* g, void* l) {
  __builtin_amdgcn_global_load_lds(
      (const __attribute__((address_space(1))) void*)g,
      (__attribute__((address_space(3))) void*)l, 16, 0, 0);
}

__device__ inline void barrier_raw() {
  asm volatile("" ::: "memory");
  __builtin_amdgcn_s_barrier();
  asm volatile("" ::: "memory");
}

#define VMCNT(N) asm volatile("s_waitcnt vmcnt(" #N ")" ::: "memory")
#define LGKM(N) asm volatile("s_waitcnt lgkmcnt(" #N ")" ::: "memory")

// ---------------- fused fp32 -> fp16 conversion (hs + 4 weights) ----------------
__global__ __launch_bounds__(256) void f2h_all(
    const float* __restrict__ hs, const float* __restrict__ w0,
    const float* __restrict__ w1, const float* __restrict__ w2,
    const float* __restrict__ w3, h16* __restrict__ dst, int hsN) {
  int i = (blockIdx.x * 256 + threadIdx.x) * 8;
  const int tot = hsN + 4 * 1048576;
  if (i >= tot) return;
  const float* src;
  int off;
  if (i < hsN) {
    src = hs; off = i;
  } else {
    int k = i - hsN;
    int seg = k >> 20;
    off = k & 1048575;
    src = seg == 0 ? w0 : seg == 1 ? w1 : seg == 2 ? w2 : w3;
  }
  float4 a = *(const float4*)(src + off);
  float4 b = *(const float4*)(src + off + 4);
  h8 o;
  o[0] = (h16)a.x; o[1] = (h16)a.y; o[2] = (h16)a.z; o[3] = (h16)a.w;
  o[4] = (h16)b.x; o[5] = (h16)b.y; o[6] = (h16)b.z; o[7] = (h16)b.w;
  *(h8*)(dst + i) = o;
}

// ---------------- QKV GEMM (round-4 exact: 256x256, BK=64, 8-phase) ----------
__global__ __launch_bounds__(512, 2) void qkv8(
    const h16* __restrict__ A, const h16* __restrict__ Bw,
    const float* __restrict__ qb, const float* __restrict__ kb,
    const float* __restrict__ vb, h16* __restrict__ qo, h16* __restrict__ ko,
    h16* __restrict__ vo, int nbm, int cpx) {
  __shared__ __align__(16) h16 Asm[2][256][64];
  __shared__ __align__(16) h16 Bsm[2][256][64];

  const int tid = threadIdx.x;
  const int wid = tid >> 6, lane = tid & 63;
  const int lr = lane & 15, lg = lane >> 4;
  const int wr = wid >> 2, wc = wid & 3;
  const int srow = wid * 8 + (lane >> 3);
  const int lsrc = ((lane & 7) ^ (srow & 7)) * 8;

  const int wg = (blockIdx.x % 8) * cpx + blockIdx.x / 8;
  const int bm = wg % nbm, bn = wg / nbm;
  const int row0 = bm * 256, col0 = bn * 256;

  const h16* Ag = A + (size_t)row0 * 1024;
  const h16* Bg = Bw + (size_t)col0 * 1024;

  auto stg = [&](const h16* g, h16* l, int rs) {
    gl2lds16(g + (size_t)(rs + srow) * 1024 + lsrc, l + (rs + wid * 8) * 64);
  };
  auto ldf = [&](const h16* base, int row, int kk) -> h8 {
    return *(const h8*)(base + row * 64 + ((kk * 4 + lg) ^ (lr & 7)) * 8);
  };

  f32x4 acc[8][4] = {};
  h8 bf[4][2], afA[2][2], afB[2][2];

  stg(Ag, &Asm[0][0][0], 0);   stg(Ag, &Asm[0][0][0], 128);
  stg(Bg, &Bsm[0][0][0], 0);   stg(Bg, &Bsm[0][0][0], 64);
  stg(Bg, &Bsm[0][0][0], 128); stg(Bg, &Bsm[0][0][0], 192);
  stg(Ag, &Asm[0][0][0], 64);  stg(Ag, &Asm[0][0][0], 192);
  VMCNT(2);
  barrier_raw();

#define MMA2(AF, M0)                                                           \
  __builtin_amdgcn_s_setprio(1);                                               \
  _Pragma("unroll") for (int kk = 0; kk < 2; ++kk)                             \
      _Pragma("unroll") for (int mi = 0; mi < 2; ++mi)                         \
          _Pragma("unroll") for (int n = 0; n < 4; ++n)                        \
              acc[(M0) + mi][n] = __builtin_amdgcn_mfma_f32_16x16x32_f16(      \
                  AF[mi][kk], bf[n][kk], acc[(M0) + mi][n], 0, 0, 0);          \
  __builtin_amdgcn_s_setprio(0)

#define TILE_PHASES(T, RBUF, WBUF)                                             \
  {                                                                            \
    const h16* Ar = &Asm[RBUF][0][0];                                          \
    const h16* Br = &Bsm[RBUF][0][0];                                          \
    h16* Aw = &Asm[WBUF][0][0];                                                \
    h16* Bwl = &Bsm[WBUF][0][0];                                               \
    const h16* Agt = Ag + (size_t)((T) + 1) * 64;                              \
    const h16* Bgt = Bg + (size_t)((T) + 1) * 64;                              \
    const bool st = (T) < 15;                                                  \
    _Pragma("unroll") for (int n = 0; n < 4; ++n) {                            \
      bf[n][0] = ldf(Br, wc * 64 + n * 16 + lr, 0);                            \
      bf[n][1] = ldf(Br, wc * 64 + n * 16 + lr, 1);                            \
    }                                                                          \
    _Pragma("unroll") for (int kk = 0; kk < 2; ++kk) {                         \
      afA[0][kk] = ldf(Ar, wr * 128 + 0 * 16 + lr, kk);                        \
      afA[1][kk] = ldf(Ar, wr * 128 + 1 * 16 + lr, kk);                        \
    }                                                                          \
    _Pragma("unroll") for (int kk = 0; kk < 2; ++kk) {                         \
      afB[0][kk] = ldf(Ar, wr * 128 + 2 * 16 + lr, kk);                        \
      afB[1][kk] = ldf(Ar, wr * 128 + 3 * 16 + lr, kk);                        \
    }                                                                          \
    if (st) { stg(Agt, Aw, 0); stg(Agt, Aw, 128); }                            \
    barrier_raw();                                                             \
    LGKM(4);                                                                   \
    MMA2(afA, 0);                                                              \
    if (st) { VMCNT(2); } else { VMCNT(0); }                                   \
    barrier_raw();                                                             \
    _Pragma("unroll") for (int kk = 0; kk < 2; ++kk) {                         \
      afA[0][kk] = ldf(Ar, wr * 128 + 4 * 16 + lr, kk);                        \
      afA[1][kk] = ldf(Ar, wr * 128 + 5 * 16 + lr, kk);                        \
    }                                                                          \
    if (st) { stg(Bgt, Bwl, 0); stg(Bgt, Bwl, 64); }                           \
    barrier_raw();                                                             \
    LGKM(4);                                                                   \
    MMA2(afB, 2);                                                              \
    barrier_raw();                                                             \
    _Pragma("unroll") for (int kk = 0; kk < 2; ++kk) {                         \
      afB[0][kk] = ldf(Ar, wr * 128 + 6 * 16 + lr, kk);                        \
      afB[1][kk] = ldf(Ar, wr * 128 + 7 * 16 + lr, kk);                        \
    }                                                                          \
    if (st) { stg(Bgt, Bwl, 128); stg(Bgt, Bwl, 192); }                        \
    barrier_raw();                                                             \
    LGKM(4);                                                                   \
    MMA2(afA, 4);                                                              \
    barrier_raw();                                                             \
    if (st) { stg(Agt, Aw, 64); stg(Agt, Aw, 192); }                           \
    barrier_raw();                                                             \
    LGKM(0);                                                                   \
    MMA2(afB, 6);                                                              \
    if (st) { VMCNT(2); } else { VMCNT(0); }                                   \
    barrier_raw();                                                             \
  }

  for (int tt = 0; tt < 16; tt += 2) {
    TILE_PHASES(tt, 0, 1);
    TILE_PHASES(tt + 1, 1, 0);
  }
#undef TILE_PHASES
#undef MMA2

  const int tsel = col0 >> 10;
  const float* bp = tsel == 0 ? qb : (tsel == 1 ? kb : vb);
  h16* outp = tsel == 0 ? qo : (tsel == 1 ? ko : vo);
#pragma unroll
  for (int n = 0; n < 4; ++n) {
    const int cidx = col0 + wc * 64 + n * 16 + lr;
    const int jj = cidx & 1023;
    const float bv = bp[jj];
    const int hh = jj >> 6, dd = jj & 63;
#pragma unroll
    for (int m = 0; m < 8; ++m) {
#pragma unroll
      for (int j = 0; j < 4; ++j) {
        const int r = row0 + wr * 128 + m * 16 + lg * 4 + j;
        const int bb = r >> 11, ss = r & 2047;
        outp[(((size_t)bb * 16 + hh) * 2048 + ss) * 64 + dd] =
            (h16)(acc[m][n][j] + bv);
      }
    }
  }
}

// ---------------- O-proj: 1-WAVE self-paced blocks, zero barriers -------------
// BM=32, BN=128, BK=64, 16 K-iters. One wave per block; LDS double-buffer
// (40 KB -> 4 blocks/CU, grid 1024 = all resident). Counted vmcnt(20) dist-1
// prefetch; vmcnt(0) only at the last iter (no staging there -- r3 lesson).
// 8-slot XOR swizzle both-sides: LDS[row][s] holds global slot s^(row&7);
// gl2lds dest linear, source col inverse-swizzled, ds_read swizzled.
// XCD-chunked grid: each XCD owns one 128-col B-panel (256 KB, L2-resident).
__global__ __launch_bounds__(64) void oproj1w(const h16* __restrict__ A,
                                              const h16* __restrict__ Bw,
                                              const float* __restrict__ b0,
                                              float* __restrict__ Cf) {
  __shared__ __align__(16) h16 Ash[2][32][64];
  __shared__ __align__(16) h16 Bsh[2][128][64];

  const int lane = threadIdx.x;
  const int lr = lane & 15, lg = lane >> 4;
  const int srw = lane >> 3;                       // staging row within a call
  const int csw = ((lane & 7) ^ (srw & 7)) * 8;    // inverse-swizzled src col

  // XCD-chunked: xcd = bid%8 owns col-panel bn = xcd? map wg = xcd*128 + bid/8
  const int wg = (blockIdx.x & 7) * 128 + (blockIdx.x >> 3);
  const int bm = wg & 127, bn = wg >> 7;
  const int row0 = bm * 32, col0 = bn * 128;

  const h16* Ag = A + (size_t)row0 * 1024;
  const h16* Bg = Bw + (size_t)col0 * 1024;

  auto stage = [&](int t, int bi) {
    const int kof = t * 64 + csw;
#pragma unroll
    for (int rs = 0; rs < 32; rs += 8)
      gl2lds16(Ag + (size_t)(rs + srw) * 1024 + kof, &Ash[bi][rs][0]);
#pragma unroll
    for (int rs = 0; rs < 128; rs += 8)
      gl2lds16(Bg + (size_t)(rs + srw) * 1024 + kof, &Bsh[bi][rs][0]);
  };
  auto ldf = [&](const h16* base, int row, int kk) -> h8 {
    return *(const h8*)(base + row * 64 + ((kk * 4 + lg) ^ (row & 7)) * 8);
  };

  f32x4 acc[2][8] = {};

  stage(0, 0);
  for (int t = 0; t < 16; ++t) {
    if (t + 1 < 16) {
      stage(t + 1, (t + 1) & 1);
      VMCNT(20);   // tile t's 20 calls landed; t+1's 20 in flight
    } else {
      VMCNT(0);    // nothing staged this iter: counted wait would be vacuous
    }
    const h16* Ar = &Ash[t & 1][0][0];
    const h16* Br = &Bsh[t & 1][0][0];
    h8 af[2][2], bf[8][2];
#pragma unroll
    for (int m = 0; m < 2; ++m)
#pragma unroll
      for (int kk = 0; kk < 2; ++kk) af[m][kk] = ldf(Ar, m * 16 + lr, kk);
#pragma unroll
    for (int n = 0; n < 8; ++n)
#pragma unroll
      for (int kk = 0; kk < 2; ++kk) bf[n][kk] = ldf(Br, n * 16 + lr, kk);
    __builtin_amdgcn_s_setprio(1);
#pragma unroll
    for (int m = 0; m < 2; ++m)
#pragma unroll
      for (int n = 0; n < 8; ++n)
#pragma unroll
        for (int kk = 0; kk < 2; ++kk)
          acc[m][n] = __builtin_amdgcn_mfma_f32_16x16x32_f16(af[m][kk], bf[n][kk],
                                                             acc[m][n], 0, 0, 0);
    __builtin_amdgcn_s_setprio(0);
  }

#pragma unroll
  for (int n = 0; n < 8; ++n) {
    const int cidx = col0 + n * 16 + lr;
    const float bv = b0[cidx];
#pragma unroll
    for (int m = 0; m < 2; ++m)
#pragma unroll
      for (int j = 0; j < 4; ++j) {
        const int r = row0 + m * 16 + lg * 4 + j;
        Cf[(size_t)r * 1024 + cidx] = acc[m][n][j] + bv;
      }
  }
}

// ---------------- sliding-window attention (unchanged) ----------------
__global__ __launch_bounds__(256) void swattn(const h16* __restrict__ Q,
                                              const h16* __restrict__ K,
                                              const h16* __restrict__ V,
                                              h16* __restrict__ O) {
  __shared__ __align__(16) h16 Ksh[128 * 72];
  __shared__ __align__(16) h16 Vsh[64 * 136];
  __shared__ __align__(16) h16 Psh[4][16 * 136];

  const int qb0 = blockIdx.x * 64;
  const int bh = blockIdx.y;
  const int b = bh >> 4, h = bh & 15;
  const int tid = threadIdx.x;
  const int wave = tid >> 6, lane = tid & 63;
  const int lr = lane & 15, lg = lane >> 4;

  const h16* Qb = Q + (size_t)bh * 2048 * 64;
  const h16* Kb = K + (size_t)bh * 2048 * 64;
  const h16* Vb = V + (size_t)bh * 2048 * 64;

#pragma unroll
  for (int i = 0; i < 4; ++i) {
    const int c = tid * 4 + i;
    const int row = c >> 3, c8 = c & 7;
    const int t = qb0 - 32 + row;
    h8 kv, vv;
    if (t >= 0 && t < 2048) {
      kv = *(const h8*)&Kb[(size_t)t * 64 + c8 * 8];
      vv = *(const h8*)&Vb[(size_t)t * 64 + c8 * 8];
    } else {
#pragma unroll
      for (int j = 0; j < 8; ++j) { kv[j] = (h16)0.f; vv[j] = (h16)0.f; }
    }
    *(h8*)&Ksh[row * 72 + c8 * 8] = kv;
#pragma unroll
    for (int j = 0; j < 8; ++j) Vsh[(c8 * 8 + j) * 136 + row] = vv[j];
  }
  __syncthreads();

  const int qrow = qb0 + wave * 16 + lr;
  h8 qa[2];
#pragma unroll
  for (int kk = 0; kk < 2; ++kk)
    qa[kk] = *(const h8*)&Qb[(size_t)qrow * 64 + kk * 32 + lg * 8];

  f32x4 sacc[8] = {};
#pragma unroll
  for (int n = 0; n < 8; ++n)
#pragma unroll
    for (int kk = 0; kk < 2; ++kk) {
      h8 kb = *(const h8*)&Ksh[(n * 16 + lr) * 72 + kk * 32 + lg * 8];
      sacc[n] = __builtin_amdgcn_mfma_f32_16x16x32_f16(qa[kk], kb, sacc[n], 0, 0, 0);
    }

  float p[8][4];
#pragma unroll
  for (int j = 0; j < 4; ++j) {
    const int wrow = wave * 16 + lg * 4 + j;
    float mx = -1e30f;
#pragma unroll
    for (int n = 0; n < 8; ++n) {
      const int d = n * 16 + lr - wrow;
      float s = (d < 0 || d > 64) ? -1e30f : sacc[n][j] * 0.125f;
      p[n][j] = s;
      mx = fmaxf(mx, s);
    }
#pragma unroll
    for (int off = 1; off < 16; off <<= 1) mx = fmaxf(mx, __shfl_xor(mx, off, 64));
    float sum = 0.f;
#pragma unroll
    for (int n = 0; n < 8; ++n) {
      const float e = __expf(p[n][j] - mx);
      p[n][j] = e;
      sum += e;
    }
#pragma unroll
    for (int off = 1; off < 16; off <<= 1) sum += __shfl_xor(sum, off, 64);
    const float inv = 1.f / sum;
#pragma unroll
    for (int n = 0; n < 8; ++n) p[n][j] *= inv;
  }

#pragma unroll
  for (int n = 0; n < 8; ++n)
#pragma unroll
    for (int j = 0; j < 4; ++j)
      Psh[wave][(lg * 4 + j) * 136 + n * 16 + lr] = (h16)p[n][j];
  __syncthreads();

  f32x4 oacc[4] = {};
#pragma unroll
  for (int kk = 0; kk < 4; ++kk) {
    h8 pa = *(const h8*)&Psh[wave][lr * 136 + kk * 32 + lg * 8];
#pragma unroll
    for (int n = 0; n < 4; ++n) {
      h8 vb = *(const h8*)&Vsh[(n * 16 + lr) * 136 + kk * 32 + lg * 8];
      oacc[n] = __builtin_amdgcn_mfma_f32_16x16x32_f16(pa, vb, oacc[n], 0, 0, 0);
    }
  }

#pragma unroll
  for (int n = 0; n < 4; ++n)
#pragma unroll
    for (int j = 0; j < 4; ++j) {
      const int s = qb0 + wave * 16 + lg * 4 + j;
      const int d = n * 16 + lr;
      O[((size_t)b * 2048 + s) * 1024 + h * 64 + d] = (h16)oacc[n][j];
    }
}

extern "C" void kernel_launch(void* const* d_in, const int* in_sizes, int n_in,
                              void* d_out, int out_size, void* d_ws, size_t ws_size,
                              hipStream_t stream) {
  const float* hs = (const float*)d_in[0];
  const float* qw = (const float*)d_in[1];
  const float* qb = (const float*)d_in[2];
  const float* kw = (const float*)d_in[3];
  const float* kb = (const float*)d_in[4];
  const float* vw = (const float*)d_in[5];
  const float* vb = (const float*)d_in[6];
  const float* ow = (const float*)d_in[7];
  const float* ob = (const float*)d_in[8];

  const int M = in_sizes[0] / 1024;  // B * S = 4096

  h16* hsH = (h16*)d_ws;
  h16* wqkv = hsH + (size_t)M * 1024;           // 3072 x 1024 (q,k,v stacked)
  h16* woH = wqkv + (size_t)3072 * 1024;        // 1024 x 1024
  h16* qH = woH + (size_t)1024 * 1024;          // [B,H,S,D]
  h16* kH = qH + (size_t)M * 1024;
  h16* vH = kH + (size_t)M * 1024;
  h16* attnH = vH + (size_t)M * 1024;           // [B,S,E]

  const int tot = M * 1024 + 4 * 1048576;
  f2h_all<<<(tot / 8 + 255) / 256, 256, 0, stream>>>(hs, qw, kw, vw, ow, hsH,
                                                     M * 1024);

  const int nbm = M / 256;
  const int nwg = nbm * 12;
  qkv8<<<nwg, 512, 0, stream>>>(hsH, wqkv, qb, kb, vb, qH, kH, vH, nbm, nwg / 8);

  swattn<<<dim3(32, M / 2048 * 16), 256, 0, stream>>>(qH, kH, vH, attnH);

  // O-proj: 1024 one-wave blocks (128 row-tiles x 8 col-panels), 4/CU resident
  oproj1w<<<1024, 64, 0, stream>>>(attnH, woH, ob, (float*)d_out);
}

// Round 7
// 86.654 us; speedup vs baseline: 1.1132x; 1.0018x over previous
//
#include <hip/hip_runtime.h>
#include <math.h>

typedef _Float16 h16;
typedef _Float16 h8 __attribute__((ext_vector_type(8)));
typedef float f32x4 __attribute__((ext_vector_type(4)));

__device__ inline void gl2lds16(const void* g, void* l) {
  __builtin_amdgcn_global_load_lds(
      (const __attribute__((address_space(1))) void*)g,
      (__attribute__((address_space(3))) void*)l, 16, 0, 0);
}

#define VMCNT(N) asm volatile("s_waitcnt vmcnt(" #N ")" ::: "memory")

// ---------------- fused fp32 -> fp16 conversion (hs + 4 weights) ----------------
__global__ __launch_bounds__(256) void f2h_all(
    const float* __restrict__ hs, const float* __restrict__ w0,
    const float* __restrict__ w1, const float* __restrict__ w2,
    const float* __restrict__ w3, h16* __restrict__ dst, int hsN) {
  int i = (blockIdx.x * 256 + threadIdx.x) * 8;
  const int tot = hsN + 4 * 1048576;
  if (i >= tot) return;
  const float* src;
  int off;
  if (i < hsN) {
    src = hs; off = i;
  } else {
    int k = i - hsN;
    int seg = k >> 20;
    off = k & 1048575;
    src = seg == 0 ? w0 : seg == 1 ? w1 : seg == 2 ? w2 : w3;
  }
  float4 a = *(const float4*)(src + off);
  float4 b = *(const float4*)(src + off + 4);
  h8 o;
  o[0] = (h16)a.x; o[1] = (h16)a.y; o[2] = (h16)a.z; o[3] = (h16)a.w;
  o[4] = (h16)b.x; o[5] = (h16)b.y; o[6] = (h16)b.z; o[7] = (h16)b.w;
  *(h8*)(dst + i) = o;
}

// ---------------- QKV GEMM: m97 structure, 128x128, BK=32, 3 blocks/CU ---------
// 768 blocks / 256 CUs = 3 co-resident blocks per CU -> implicit latency hiding
// (m114). Swizzle (r5-verified, PMC 0 conflicts): LDS[row][s] holds global slot
// s ^ ((row>>1)&3); linear gl2lds dest, inverse-swizzled global source col,
// swizzled ds_read. Epilogue: acc -> LDS (pad 136) -> h8 -> full-line stores,
// row-major [B,S,E] per q/k/v (no scatter, no RMW).
__global__ __launch_bounds__(256) void qkv97(
    const h16* __restrict__ A, const h16* __restrict__ Bw,
    const float* __restrict__ qb, const float* __restrict__ kb,
    const float* __restrict__ vb, h16* __restrict__ qo, h16* __restrict__ ko,
    h16* __restrict__ vo) {
  __shared__ __align__(16) h16 Ash[128 * 32];
  __shared__ __align__(16) h16 Bsh[128 * 32];
  __shared__ __align__(16) h16 Csh[128 * 136];

  const int tid = threadIdx.x;
  const int wid = tid >> 6, lane = tid & 63;
  const int lr = lane & 15, lg = lane >> 4;
  const int wr = wid >> 1, wc = wid & 1;
  const int srow = tid >> 2;                       // staging row (0..63)
  const int csw = ((tid & 3) ^ ((srow >> 1) & 3)) * 8;  // inv-swizzled src col

  // XCD-chunked mapping: 768 blocks, 96 per XCD; each XCD covers 3 bn panels.
  const int wg = (blockIdx.x & 7) * 96 + (blockIdx.x >> 3);
  const int bm = wg & 31, bn = wg >> 5;
  const int row0 = bm * 128, col0 = bn * 128;

  const h16* Ag = A + (size_t)row0 * 1024;
  const h16* Bg = Bw + (size_t)col0 * 1024;

  auto ldf = [&](const h16* base, int row) -> h8 {
    return *(const h8*)(base + row * 32 + (lg ^ ((row >> 1) & 3)) * 8);
  };

  f32x4 acc[4][4] = {};

  for (int t = 0; t < 32; ++t) {
    const int kof = t * 32 + csw;
    gl2lds16(Ag + (size_t)srow * 1024 + kof, &Ash[(wid * 16) * 32]);
    gl2lds16(Ag + (size_t)(64 + srow) * 1024 + kof, &Ash[(64 + wid * 16) * 32]);
    gl2lds16(Bg + (size_t)srow * 1024 + kof, &Bsh[(wid * 16) * 32]);
    gl2lds16(Bg + (size_t)(64 + srow) * 1024 + kof, &Bsh[(64 + wid * 16) * 32]);
    __syncthreads();  // drains vmcnt(0): staged tile visible to all waves
    h8 af[4], bf[4];
#pragma unroll
    for (int m = 0; m < 4; ++m) af[m] = ldf(Ash, wr * 64 + m * 16 + lr);
#pragma unroll
    for (int n = 0; n < 4; ++n) bf[n] = ldf(Bsh, wc * 64 + n * 16 + lr);
    __builtin_amdgcn_s_setprio(1);
#pragma unroll
    for (int m = 0; m < 4; ++m)
#pragma unroll
      for (int n = 0; n < 4; ++n)
        acc[m][n] =
            __builtin_amdgcn_mfma_f32_16x16x32_f16(af[m], bf[n], acc[m][n], 0, 0, 0);
    __builtin_amdgcn_s_setprio(0);
    __syncthreads();  // all reads done before next stage overwrites
  }

  // epilogue: bias + LDS bounce -> coalesced row-major [B,S,E] writes
  const int tsel = bn >> 3;             // 0:q 1:k 2:v  (bn 0..23)
  const int colseg = (bn & 7) * 128;    // col within E
  const float* bp = tsel == 0 ? qb : (tsel == 1 ? kb : vb);
  h16* outp = tsel == 0 ? qo : (tsel == 1 ? ko : vo);

#pragma unroll
  for (int n = 0; n < 4; ++n) {
    const int ccol = wc * 64 + n * 16 + lr;
    const float bv = bp[colseg + ccol];
#pragma unroll
    for (int m = 0; m < 4; ++m)
#pragma unroll
      for (int j = 0; j < 4; ++j)
        Csh[(wr * 64 + m * 16 + lg * 4 + j) * 136 + ccol] =
            (h16)(acc[m][n][j] + bv);
  }
  __syncthreads();
#pragma unroll
  for (int p = 0; p < 8; ++p) {
    const int idx = p * 256 + tid;
    const int r = idx >> 4, c = idx & 15;
    h8 v = *(const h8*)&Csh[r * 136 + c * 8];
    *(h8*)&outp[(size_t)(row0 + r) * 1024 + colseg + c * 8] = v;
  }
}

// ---------------- O-proj: 1-wave self-paced blocks (r6, unchanged) -------------
__global__ __launch_bounds__(64) void oproj1w(const h16* __restrict__ A,
                                              const h16* __restrict__ Bw,
                                              const float* __restrict__ b0,
                                              float* __restrict__ Cf) {
  __shared__ __align__(16) h16 Ash[2][32][64];
  __shared__ __align__(16) h16 Bsh[2][128][64];

  const int lane = threadIdx.x;
  const int lr = lane & 15, lg = lane >> 4;
  const int srw = lane >> 3;
  const int csw = ((lane & 7) ^ (srw & 7)) * 8;

  const int wg = (blockIdx.x & 7) * 128 + (blockIdx.x >> 3);
  const int bm = wg & 127, bn = wg >> 7;
  const int row0 = bm * 32, col0 = bn * 128;

  const h16* Ag = A + (size_t)row0 * 1024;
  const h16* Bg = Bw + (size_t)col0 * 1024;

  auto stage = [&](int t, int bi) {
    const int kof = t * 64 + csw;
#pragma unroll
    for (int rs = 0; rs < 32; rs += 8)
      gl2lds16(Ag + (size_t)(rs + srw) * 1024 + kof, &Ash[bi][rs][0]);
#pragma unroll
    for (int rs = 0; rs < 128; rs += 8)
      gl2lds16(Bg + (size_t)(rs + srw) * 1024 + kof, &Bsh[bi][rs][0]);
  };
  auto ldf = [&](const h16* base, int row, int kk) -> h8 {
    return *(const h8*)(base + row * 64 + ((kk * 4 + lg) ^ (row & 7)) * 8);
  };

  f32x4 acc[2][8] = {};

  stage(0, 0);
  for (int t = 0; t < 16; ++t) {
    if (t + 1 < 16) {
      stage(t + 1, (t + 1) & 1);
      VMCNT(20);
    } else {
      VMCNT(0);
    }
    const h16* Ar = &Ash[t & 1][0][0];
    const h16* Br = &Bsh[t & 1][0][0];
    h8 af[2][2], bf[8][2];
#pragma unroll
    for (int m = 0; m < 2; ++m)
#pragma unroll
      for (int kk = 0; kk < 2; ++kk) af[m][kk] = ldf(Ar, m * 16 + lr, kk);
#pragma unroll
    for (int n = 0; n < 8; ++n)
#pragma unroll
      for (int kk = 0; kk < 2; ++kk) bf[n][kk] = ldf(Br, n * 16 + lr, kk);
    __builtin_amdgcn_s_setprio(1);
#pragma unroll
    for (int m = 0; m < 2; ++m)
#pragma unroll
      for (int n = 0; n < 8; ++n)
#pragma unroll
        for (int kk = 0; kk < 2; ++kk)
          acc[m][n] = __builtin_amdgcn_mfma_f32_16x16x32_f16(af[m][kk], bf[n][kk],
                                                             acc[m][n], 0, 0, 0);
    __builtin_amdgcn_s_setprio(0);
  }

#pragma unroll
  for (int n = 0; n < 8; ++n) {
    const int cidx = col0 + n * 16 + lr;
    const float bv = b0[cidx];
#pragma unroll
    for (int m = 0; m < 2; ++m)
#pragma unroll
      for (int j = 0; j < 4; ++j) {
        const int r = row0 + m * 16 + lg * 4 + j;
        Cf[(size_t)r * 1024 + cidx] = acc[m][n][j] + bv;
      }
  }
}

// ---------------- sliding-window attention ([B,S,E] inputs) ----------------
__global__ __launch_bounds__(256) void swattn(const h16* __restrict__ Q,
                                              const h16* __restrict__ K,
                                              const h16* __restrict__ V,
                                              h16* __restrict__ O) {
  __shared__ __align__(16) h16 Ksh[128 * 72];
  __shared__ __align__(16) h16 Vsh[64 * 136];
  __shared__ __align__(16) h16 Psh[4][16 * 136];

  const int qb0 = blockIdx.x * 64;
  const int bh = blockIdx.y;
  const int b = bh >> 4, h = bh & 15;
  const int tid = threadIdx.x;
  const int wave = tid >> 6, lane = tid & 63;
  const int lr = lane & 15, lg = lane >> 4;

  // [B,S,E] layout: row stride 1024, head offset h*64
  const h16* Qb = Q + (size_t)b * 2048 * 1024 + h * 64;
  const h16* Kb = K + (size_t)b * 2048 * 1024 + h * 64;
  const h16* Vb = V + (size_t)b * 2048 * 1024 + h * 64;

#pragma unroll
  for (int i = 0; i < 4; ++i) {
    const int c = tid * 4 + i;
    const int row = c >> 3, c8 = c & 7;
    const int t = qb0 - 32 + row;
    h8 kv, vv;
    if (t >= 0 && t < 2048) {
      kv = *(const h8*)&Kb[(size_t)t * 1024 + c8 * 8];
      vv = *(const h8*)&Vb[(size_t)t * 1024 + c8 * 8];
    } else {
#pragma unroll
      for (int j = 0; j < 8; ++j) { kv[j] = (h16)0.f; vv[j] = (h16)0.f; }
    }
    *(h8*)&Ksh[row * 72 + c8 * 8] = kv;
#pragma unroll
    for (int j = 0; j < 8; ++j) Vsh[(c8 * 8 + j) * 136 + row] = vv[j];
  }
  __syncthreads();

  const int qrow = qb0 + wave * 16 + lr;
  h8 qa[2];
#pragma unroll
  for (int kk = 0; kk < 2; ++kk)
    qa[kk] = *(const h8*)&Qb[(size_t)qrow * 1024 + kk * 32 + lg * 8];

  f32x4 sacc[8] = {};
#pragma unroll
  for (int n = 0; n < 8; ++n)
#pragma unroll
    for (int kk = 0; kk < 2; ++kk) {
      h8 kb = *(const h8*)&Ksh[(n * 16 + lr) * 72 + kk * 32 + lg * 8];
      sacc[n] = __builtin_amdgcn_mfma_f32_16x16x32_f16(qa[kk], kb, sacc[n], 0, 0, 0);
    }

  float p[8][4];
#pragma unroll
  for (int j = 0; j < 4; ++j) {
    const int wrow = wave * 16 + lg * 4 + j;
    float mx = -1e30f;
#pragma unroll
    for (int n = 0; n < 8; ++n) {
      const int d = n * 16 + lr - wrow;
      float s = (d < 0 || d > 64) ? -1e30f : sacc[n][j] * 0.125f;
      p[n][j] = s;
      mx = fmaxf(mx, s);
    }
#pragma unroll
    for (int off = 1; off < 16; off <<= 1) mx = fmaxf(mx, __shfl_xor(mx, off, 64));
    float sum = 0.f;
#pragma unroll
    for (int n = 0; n < 8; ++n) {
      const float e = __expf(p[n][j] - mx);
      p[n][j] = e;
      sum += e;
    }
#pragma unroll
    for (int off = 1; off < 16; off <<= 1) sum += __shfl_xor(sum, off, 64);
    const float inv = 1.f / sum;
#pragma unroll
    for (int n = 0; n < 8; ++n) p[n][j] *= inv;
  }

#pragma unroll
  for (int n = 0; n < 8; ++n)
#pragma unroll
    for (int j = 0; j < 4; ++j)
      Psh[wave][(lg * 4 + j) * 136 + n * 16 + lr] = (h16)p[n][j];
  __syncthreads();

  f32x4 oacc[4] = {};
#pragma unroll
  for (int kk = 0; kk < 4; ++kk) {
    h8 pa = *(const h8*)&Psh[wave][lr * 136 + kk * 32 + lg * 8];
#pragma unroll
    for (int n = 0; n < 4; ++n) {
      h8 vb = *(const h8*)&Vsh[(n * 16 + lr) * 136 + kk * 32 + lg * 8];
      oacc[n] = __builtin_amdgcn_mfma_f32_16x16x32_f16(pa, vb, oacc[n], 0, 0, 0);
    }
  }

#pragma unroll
  for (int n = 0; n < 4; ++n)
#pragma unroll
    for (int j = 0; j < 4; ++j) {
      const int s = qb0 + wave * 16 + lg * 4 + j;
      const int d = n * 16 + lr;
      O[((size_t)b * 2048 + s) * 1024 + h * 64 + d] = (h16)oacc[n][j];
    }
}

extern "C" void kernel_launch(void* const* d_in, const int* in_sizes, int n_in,
                              void* d_out, int out_size, void* d_ws, size_t ws_size,
                              hipStream_t stream) {
  const float* hs = (const float*)d_in[0];
  const float* qw = (const float*)d_in[1];
  const float* qb = (const float*)d_in[2];
  const float* kw = (const float*)d_in[3];
  const float* kb = (const float*)d_in[4];
  const float* vw = (const float*)d_in[5];
  const float* vb = (const float*)d_in[6];
  const float* ow = (const float*)d_in[7];
  const float* ob = (const float*)d_in[8];

  const int M = in_sizes[0] / 1024;  // B * S = 4096

  h16* hsH = (h16*)d_ws;
  h16* wqkv = hsH + (size_t)M * 1024;           // 3072 x 1024 (q,k,v stacked)
  h16* woH = wqkv + (size_t)3072 * 1024;        // 1024 x 1024
  h16* qH = woH + (size_t)1024 * 1024;          // [B,S,E]
  h16* kH = qH + (size_t)M * 1024;
  h16* vH = kH + (size_t)M * 1024;
  h16* attnH = vH + (size_t)M * 1024;           // [B,S,E]

  const int tot = M * 1024 + 4 * 1048576;
  f2h_all<<<(tot / 8 + 255) / 256, 256, 0, stream>>>(hs, qw, kw, vw, ow, hsH,
                                                     M * 1024);

  // QKV: 128x128 tiles, grid 32x24 = 768 -> 3 blocks/CU
  qkv97<<<768, 256, 0, stream>>>(hsH, wqkv, qb, kb, vb, qH, kH, vH);

  swattn<<<dim3(32, M / 2048 * 16), 256, 0, stream>>>(qH, kH, vH, attnH);

  // O-proj: 1024 one-wave blocks (128 row-tiles x 8 col-panels), 4/CU resident
  oproj1w<<<1024, 64, 0, stream>>>(attnH, woH, ob, (float*)d_out);
}